// Round 1
// baseline (407.775 us; speedup 1.0000x reference)
//
#include <hip/hip_runtime.h>
#include <math.h>

#define B_ 4
#define C_ 256
#define O_ 256
#define H_ 64
#define W_ 64
#define HW_ 4096
#define K9 9
#define KK_ 2304   // C_*K9
#define N_ 16384   // B_*HW_

typedef _Float16 f16x8 __attribute__((ext_vector_type(8)));
typedef float f32x4 __attribute__((ext_vector_type(4)));

// ws layout (bytes):
//   Wt    f16 [O_][KK_]      @ 0         1,179,648   (kk = cb*288 + k*32 + cloc, c = cb*32+cloc)
//   scale f32 [256]          @ 1179648   1,024
//   shift f32 [256]          @ 1180672   1,024
//   pk    u32 [9][N_]        @ 1181696   589,824     (idx00 | dx<<12 | dy<<13)
//   wgt   f32 [4][9][N_]     @ 1771520   2,359,296   (bilinear*valid*mask, per corner)
//   total 4,130,816 B

static __device__ __forceinline__ unsigned short f2h(float f) {
  _Float16 h = (_Float16)f;
  return __builtin_bit_cast(unsigned short, h);
}

// ---------------- prep: permute+cast weight, fold BN ----------------
__global__ __launch_bounds__(256) void prep_kernel(
    const float* __restrict__ weight, const float* __restrict__ bias,
    const float* __restrict__ gamma, const float* __restrict__ beta,
    const float* __restrict__ rmean, const float* __restrict__ rvar,
    unsigned short* __restrict__ Wt, float* __restrict__ scale, float* __restrict__ shift) {
  int o = blockIdx.x;
  int tid = threadIdx.x;
#pragma unroll
  for (int j = 0; j < 9; ++j) {
    int wk = tid + j * 256;          // 0..2303
    int cb = wk / 288;
    int rem = wk - cb * 288;
    int k = rem >> 5;
    int cloc = rem & 31;
    int c = cb * 32 + cloc;
    Wt[o * KK_ + wk] = f2h(weight[(o * C_ + c) * 9 + k]);
  }
  if (blockIdx.x == 0) {
    float inv = rsqrtf(rvar[tid] + 1e-5f);
    float sc = gamma[tid] * inv;
    scale[tid] = sc;
    shift[tid] = beta[tid] + sc * (bias[tid] - rmean[tid]);
  }
}

// ---------------- offset conv (27ch) + per-(k,n) sample precompute ----------------
__global__ __launch_bounds__(512) void offconv_kernel(
    const float* __restrict__ x, const float* __restrict__ w_off,
    const float* __restrict__ b_off,
    unsigned int* __restrict__ pk, float* __restrict__ wgt) {
  int b = blockIdx.x >> 6;
  int h = blockIdx.x & 63;
  int tid = threadIdx.x;
  int w = tid & 63;
  int csub = tid >> 6;               // 0..7, c-partition
  __shared__ float pm[8 * 27 * 64];  // 55,296 B partials
  __shared__ float om[27 * 64];      // reduced offsets/mask

  const float* xb = x + b * (C_ * HW_);
  float acc[27];
#pragma unroll
  for (int d = 0; d < 27; ++d) acc[d] = 0.f;

  bool r0 = (h - 1 >= 0), r2 = (h + 1 < 64);
  int xm1 = w - 1, xp1 = w + 1;
  bool c0ok = (xm1 >= 0), c2ok = (xp1 < 64);

  for (int i = 0; i < 32; ++i) {
    int c = csub * 32 + i;
    int cu = __builtin_amdgcn_readfirstlane(c);  // wave-uniform
    const float* xp = xb + c * HW_;
    float xv[9];
    {
      const float* r = xp + (h - 1) * 64;
      xv[0] = (r0 && c0ok) ? r[xm1] : 0.f;
      xv[1] = r0 ? r[w] : 0.f;
      xv[2] = (r0 && c2ok) ? r[xp1] : 0.f;
    }
    {
      const float* r = xp + h * 64;
      xv[3] = c0ok ? r[xm1] : 0.f;
      xv[4] = r[w];
      xv[5] = c2ok ? r[xp1] : 0.f;
    }
    {
      const float* r = xp + (h + 1) * 64;
      xv[6] = (r2 && c0ok) ? r[xm1] : 0.f;
      xv[7] = r2 ? r[w] : 0.f;
      xv[8] = (r2 && c2ok) ? r[xp1] : 0.f;
    }
    const float* wp = w_off + cu * 9;
#pragma unroll
    for (int d = 0; d < 27; ++d) {
      const float* wd = wp + d * (C_ * 9);
#pragma unroll
      for (int t = 0; t < 9; ++t) acc[d] = fmaf(xv[t], wd[t], acc[d]);
    }
  }
#pragma unroll
  for (int d = 0; d < 27; ++d) pm[(csub * 27 + d) * 64 + w] = acc[d];
  __syncthreads();
  for (int it = tid; it < 27 * 64; it += 512) {
    int d = it >> 6, w2 = it & 63;
    float s = b_off[d];
#pragma unroll
    for (int cs = 0; cs < 8; ++cs) s += pm[(cs * 27 + d) * 64 + w2];
    om[it] = s;
  }
  __syncthreads();
  for (int it = tid; it < 9 * 64; it += 512) {
    int k = it >> 6, w2 = it & 63;
    int ky = k / 3, kx = k - 3 * ky;
    float dy = om[k * 64 + w2];
    float dx = om[(k + 9) * 64 + w2];
    float ms = 1.f / (1.f + expf(-om[(k + 18) * 64 + w2]));
    float py = dy + (float)(h - 1 + ky);
    float px = dx + (float)(w2 - 1 + kx);
    float fy0 = floorf(py), fx0 = floorf(px);
    float ly = py - fy0, lx = px - fx0;
    int iy0 = (int)fy0, ix0 = (int)fx0;
    bool vy0 = (iy0 >= 0) && (iy0 < 64);
    bool vy1 = (iy0 + 1 >= 0) && (iy0 + 1 < 64);
    bool vx0 = (ix0 >= 0) && (ix0 < 64);
    bool vx1 = (ix0 + 1 >= 0) && (ix0 + 1 < 64);
    int yA = min(max(iy0, 0), 63), yB = min(max(iy0 + 1, 0), 63);
    int xA = min(max(ix0, 0), 63), xB = min(max(ix0 + 1, 0), 63);
    unsigned int pkv = (unsigned)(yA * 64 + xA) | ((unsigned)(xB - xA) << 12) |
                       ((unsigned)(yB - yA) << 13);
    int n = blockIdx.x * 64 + w2;  // = b*4096 + h*64 + w2
    pk[k * N_ + n] = pkv;
    wgt[(0 * 9 + k) * N_ + n] = (1.f - ly) * (1.f - lx) * ms * ((vy0 && vx0) ? 1.f : 0.f);
    wgt[(1 * 9 + k) * N_ + n] = (1.f - ly) * lx * ms * ((vy0 && vx1) ? 1.f : 0.f);
    wgt[(2 * 9 + k) * N_ + n] = ly * (1.f - lx) * ms * ((vy1 && vx0) ? 1.f : 0.f);
    wgt[(3 * 9 + k) * N_ + n] = ly * lx * ms * ((vy1 && vx1) ? 1.f : 0.f);
  }
}

// ---------------- fused sample + GEMM + BN + ReLU ----------------
// BM=256 (all o), BN=32. 512 thr = 8 waves: wm=wid>>1 (o 64-range), wn=wid&1 (n 16-range).
// LDS B-tile valT[32 n][288+8 pad] f16, single-buffered; K-chunk = 32c*9k = 288.
__global__ __launch_bounds__(512) void main_kernel(
    const float* __restrict__ x, const unsigned short* __restrict__ Wt,
    const unsigned int* __restrict__ pk, const float* __restrict__ wgt,
    const float* __restrict__ scale, const float* __restrict__ shift,
    float* __restrict__ out) {
  __shared__ short valT[32 * 296];  // row stride 592 B (+16B pad → 2-way bank alias only)
  int tid = threadIdx.x;
  int nbase = blockIdx.x * 32;
  int b = nbase >> 12;
  int h = (nbase >> 6) & 63;
  int wbase = nbase & 63;  // 0 or 32
  const float* xb = x + b * (C_ * HW_);

  int lane = tid & 63;
  int wid = tid >> 6;
  int wm = wid >> 1;
  int wn = wid & 1;

  int sn = tid & 31;    // staging pixel
  int csub = tid >> 5;  // 0..15 → cloc = 2*csub
  int nglob = nbase + sn;

  f32x4 acc[4];
#pragma unroll
  for (int m = 0; m < 4; ++m) acc[m] = (f32x4){0.f, 0.f, 0.f, 0.f};

  for (int cb = 0; cb < 8; ++cb) {
    {  // ---- stage val[n][k*32+cloc] for c = cb*32 + 2*csub + {0,1} ----
      const float* xp0 = xb + (cb * 32 + csub * 2) * HW_;
      const float* xp1 = xp0 + HW_;
      char* ldsrow = (char*)valT + sn * 592 + csub * 4;
#pragma unroll
      for (int k = 0; k < 9; ++k) {
        unsigned int pkv = pk[k * N_ + nglob];
        float w00 = wgt[(0 * 9 + k) * N_ + nglob];
        float w01 = wgt[(1 * 9 + k) * N_ + nglob];
        float w10 = wgt[(2 * 9 + k) * N_ + nglob];
        float w11 = wgt[(3 * 9 + k) * N_ + nglob];
        int i00 = pkv & 0xFFF;
        int dxb = (pkv >> 12) & 1;
        int i10 = i00 + (((pkv >> 13) & 1) << 6);
        int i01 = i00 + dxb;
        int i11 = i10 + dxb;
        float v0 = w00 * xp0[i00] + w01 * xp0[i01] + w10 * xp0[i10] + w11 * xp0[i11];
        float v1 = w00 * xp1[i00] + w01 * xp1[i01] + w10 * xp1[i10] + w11 * xp1[i11];
        *(unsigned int*)(ldsrow + k * 64) = (unsigned)f2h(v0) | ((unsigned)f2h(v1) << 16);
      }
    }
    __syncthreads();
    {  // ---- 9 MFMA K-steps on this 288-chunk ----
      const char* ldsb = (const char*)valT + (wn * 16 + (lane & 15)) * 592 + (lane >> 4) * 16;
      const unsigned short* wtb =
          Wt + (wm * 64 + (lane & 15)) * KK_ + cb * 288 + (lane >> 4) * 8;
#pragma unroll
      for (int ks = 0; ks < 9; ++ks) {
        f16x8 bfrag = *(const f16x8*)(ldsb + ks * 64);
#pragma unroll
        for (int m = 0; m < 4; ++m) {
          f16x8 afrag = *(const f16x8*)(wtb + m * 16 * KK_ + ks * 32);
          acc[m] = __builtin_amdgcn_mfma_f32_16x16x32_f16(afrag, bfrag, acc[m], 0, 0, 0);
        }
      }
    }
    __syncthreads();
  }
  // ---- epilogue: BN + ReLU, C/D layout col=lane&15, row=(lane>>4)*4+r ----
  int col = wn * 16 + (lane & 15);
  int wq = wbase + col;
  int rbase = (lane >> 4) * 4;
#pragma unroll
  for (int m = 0; m < 4; ++m) {
#pragma unroll
    for (int r = 0; r < 4; ++r) {
      int o = wm * 64 + m * 16 + rbase + r;
      float v = fmaxf(scale[o] * acc[m][r] + shift[o], 0.f);
      out[(b * O_ + o) * HW_ + h * 64 + wq] = v;
    }
  }
}

extern "C" void kernel_launch(void* const* d_in, const int* in_sizes, int n_in,
                              void* d_out, int out_size, void* d_ws, size_t ws_size,
                              hipStream_t stream) {
  const float* x = (const float*)d_in[0];
  const float* w_off = (const float*)d_in[1];
  const float* b_off = (const float*)d_in[2];
  const float* weight = (const float*)d_in[3];
  const float* bias = (const float*)d_in[4];
  const float* gamma = (const float*)d_in[5];
  const float* beta = (const float*)d_in[6];
  const float* rmean = (const float*)d_in[7];
  const float* rvar = (const float*)d_in[8];
  char* ws = (char*)d_ws;
  unsigned short* Wt = (unsigned short*)ws;
  float* scale = (float*)(ws + 1179648);
  float* shift = (float*)(ws + 1180672);
  unsigned int* pk = (unsigned int*)(ws + 1181696);
  float* wgt = (float*)(ws + 1771520);
  float* out = (float*)d_out;

  prep_kernel<<<dim3(256), dim3(256), 0, stream>>>(weight, bias, gamma, beta, rmean, rvar,
                                                   Wt, scale, shift);
  offconv_kernel<<<dim3(256), dim3(512), 0, stream>>>(x, w_off, b_off, pk, wgt);
  main_kernel<<<dim3(512), dim3(512), 0, stream>>>(x, Wt, pk, wgt, scale, shift, out);
}

// Round 4
// 192.245 us; speedup vs baseline: 2.1211x; 2.1211x over previous
//
#include <hip/hip_runtime.h>
#include <math.h>

#define HW_ 4096
#define N_ 16384
#define RS 592  // LDS B-tile row stride in bytes (288 f16 + 16B pad)

typedef _Float16 f16x4 __attribute__((ext_vector_type(4)));
typedef _Float16 f16x8 __attribute__((ext_vector_type(8)));
typedef float f32x4 __attribute__((ext_vector_type(4)));

// ws layout (bytes):
//   Wt    f16 [8cb][9ks][256o][32c]  @ 0          1,179,648
//   Woff  f16 [8cb][9ks][32d][32c]   @ 1,179,648    147,456
//   scale f32 [256]                  @ 1,327,104      1,024
//   shift f32 [256]                  @ 1,328,128      1,024
//   xT    f32 [4b][4096hw][256c]     @ 1,329,152 16,777,216
//   total 18,106,368

static __device__ __forceinline__ unsigned short f2h(float f) {
  _Float16 h = (_Float16)f;
  return __builtin_bit_cast(unsigned short, h);
}
static __device__ __forceinline__ f32x4 madv(f32x4 a, float s, f32x4 c) {
  c.x = fmaf(a.x, s, c.x);
  c.y = fmaf(a.y, s, c.y);
  c.z = fmaf(a.z, s, c.z);
  c.w = fmaf(a.w, s, c.w);
  return c;
}

// ---------- setup: x transpose (blocks 0..1023) + weight prep (1024..1279) ----------
__global__ __launch_bounds__(256) void setup_kernel(
    const float* __restrict__ x, const float* __restrict__ weight,
    const float* __restrict__ w_off, const float* __restrict__ bias,
    const float* __restrict__ gamma, const float* __restrict__ beta,
    const float* __restrict__ rmean, const float* __restrict__ rvar,
    unsigned short* __restrict__ Wt, unsigned short* __restrict__ Woff,
    float* __restrict__ scale, float* __restrict__ shift, float* __restrict__ xT) {
  int bid = blockIdx.x;
  int tid = threadIdx.x;
  if (bid < 1024) {  // transpose one (b, 64-ch group, image row) tile
    __shared__ float t[64][65];
    int b = bid >> 8, cg = (bid >> 6) & 3, h = bid & 63;
    int wl = tid & 63, c4 = tid >> 6;
#pragma unroll
    for (int j = 0; j < 16; ++j) {
      int cl = j * 4 + c4;
      t[cl][wl] = x[(size_t)(b * 256 + cg * 64 + cl) * HW_ + h * 64 + wl];
    }
    __syncthreads();
    int cl2 = tid & 63, w4g = tid >> 6;
#pragma unroll
    for (int j = 0; j < 16; ++j) {
      int w2 = j * 4 + w4g;
      xT[(size_t)(b * HW_ + h * 64 + w2) * 256 + cg * 64 + cl2] = t[cl2][w2];
    }
    return;
  }
  int o = bid - 1024;  // 0..255
#pragma unroll
  for (int j = 0; j < 9; ++j) {
    int wk = tid + j * 256;  // 0..2303
    int cb = wk / 288;
    int rem = wk - cb * 288;
    int k = rem >> 5, cloc = rem & 31;
    int c = cb * 32 + cloc;
    Wt[((cb * 9 + k) * 256 + o) * 32 + cloc] = f2h(weight[(size_t)(o * 256 + c) * 9 + k]);
    if (o < 32) {
      float wv = (o < 27) ? w_off[(size_t)(o * 256 + c) * 9 + k] : 0.f;
      Woff[((cb * 9 + k) * 32 + o) * 32 + cloc] = f2h(wv);
    }
  }
  if (o == 0) {
    float inv = rsqrtf(rvar[tid] + 1e-5f);
    float sc = gamma[tid] * inv;
    scale[tid] = sc;
    shift[tid] = beta[tid] + sc * (bias[tid] - rmean[tid]);
  }
}

// ---------- fused: offset-conv MFMA -> pk/wgt in LDS -> sample+GEMM+BN+ReLU ----------
// 256 blocks (one image row), 512 thr = 8 waves. K = 2304 in 8 chunks of 288 (32c x 9k).
__global__ __launch_bounds__(512) void fused_kernel(
    const float* __restrict__ xT, const unsigned short* __restrict__ Wt,
    const unsigned short* __restrict__ Woff, const float* __restrict__ b_off,
    const float* __restrict__ scale, const float* __restrict__ shift,
    float* __restrict__ out) {
  __shared__ __align__(16) char smem[64 * RS];             // 37,888 B
  float* om_lds = (float*)smem;                            // [32][64] (union w/ valT)
  unsigned int* pk_lds = (unsigned int*)(smem + 8192);     // [9][64]
  float* w4_lds = (float*)(smem + 10496);                  // [9][64][4]

  int bid = blockIdx.x;
  int swz = (bid & 7) * 32 + (bid >> 3);  // XCD-chunked, bijective for 256
  int nbase = swz * 64;
  int b = nbase >> 12;
  int h = (nbase >> 6) & 63;

  int tid = threadIdx.x;
  int lane = tid & 63;
  int wv = tid >> 6;
  int m15 = lane & 15, q = lane >> 4;
  int sn = tid >> 3;  // staging pixel (w coord)
  int cs = tid & 7;   // staging 4-channel group

  const char* xb = (const char*)xT + (size_t)b * (HW_ * 256 * 4);

  // ======== phase 1: offset conv om[27][64] via MFMA (wave -> one 16x16 frag) ========
  int mf = wv >> 2, nf1 = wv & 3;
  f32x4 aoff = (f32x4){0.f, 0.f, 0.f, 0.f};
  for (int cb = 0; cb < 8; ++cb) {
    {  // stage direct 3x3 patch chunk as f16
      const char* xc = xb + (size_t)(cb * 32 + cs * 4) * 4;
      char* ldr = smem + sn * RS + cs * 8;
#pragma unroll
      for (int k = 0; k < 9; ++k) {
        int ky = k / 3, kx = k - 3 * (k / 3);
        int yy = h + ky - 1, xx = sn + kx - 1;
        f32x4 v = (f32x4){0.f, 0.f, 0.f, 0.f};
        if (((unsigned)yy < 64u) && ((unsigned)xx < 64u))
          v = *(const f32x4*)(xc + (size_t)(yy * 64 + xx) * 1024);
        *(f16x4*)(ldr + k * 64) = __builtin_convertvector(v, f16x4);
      }
    }
    __syncthreads();
#pragma unroll
    for (int ks = 0; ks < 9; ++ks) {
      f16x8 a = *(const f16x8*)(Woff + ((cb * 9 + ks) * 32 + mf * 16 + m15) * 32 + q * 8);
      f16x8 bb = *(const f16x8*)(smem + (nf1 * 16 + m15) * RS + ks * 64 + q * 16);
      aoff = __builtin_amdgcn_mfma_f32_16x16x32_f16(a, bb, aoff, 0, 0, 0);
    }
    __syncthreads();
  }
#pragma unroll
  for (int r = 0; r < 4; ++r)
    om_lds[(mf * 16 + q * 4 + r) * 64 + nf1 * 16 + m15] = aoff[r];
  __syncthreads();

  // ======== phase 2: pk + bilinear*mask corner weights, in LDS ========
  for (int it = tid; it < 576; it += 512) {
    int k = it >> 6, px = it & 63;
    float dy = om_lds[k * 64 + px] + b_off[k];
    float dx = om_lds[(k + 9) * 64 + px] + b_off[k + 9];
    float z = om_lds[(k + 18) * 64 + px] + b_off[k + 18];
    float ms = 1.f / (1.f + expf(-z));
    int ky = k / 3, kx = k - 3 * ky;
    float py = dy + (float)(h - 1 + ky);
    float pxf = dx + (float)(px - 1 + kx);
    float fy0 = floorf(py), fx0 = floorf(pxf);
    float ly = py - fy0, lx = pxf - fx0;
    int iy0 = (int)fy0, ix0 = (int)fx0;
    bool vy0 = (iy0 >= 0) && (iy0 < 64);
    bool vy1 = (iy0 >= -1) && (iy0 < 63);
    bool vx0 = (ix0 >= 0) && (ix0 < 64);
    bool vx1 = (ix0 >= -1) && (ix0 < 63);
    int yA = min(max(iy0, 0), 63), yB = min(max(iy0 + 1, 0), 63);
    int xA = min(max(ix0, 0), 63), xB = min(max(ix0 + 1, 0), 63);
    pk_lds[k * 64 + px] = (unsigned)(yA * 64 + xA) | ((unsigned)(xB - xA) << 12) |
                          ((unsigned)(yB - yA) << 13);
    float* wp = w4_lds + (k * 64 + px) * 4;
    wp[0] = (1.f - ly) * (1.f - lx) * ms * ((vy0 && vx0) ? 1.f : 0.f);
    wp[1] = (1.f - ly) * lx * ms * ((vy0 && vx1) ? 1.f : 0.f);
    wp[2] = ly * (1.f - lx) * ms * ((vy1 && vx0) ? 1.f : 0.f);
    wp[3] = ly * lx * ms * ((vy1 && vx1) ? 1.f : 0.f);
  }
  __syncthreads();

  // per-thread sampling params for its staging pixel
  unsigned int pkv[9];
  float wf[9][4];
#pragma unroll
  for (int k = 0; k < 9; ++k) {
    pkv[k] = pk_lds[k * 64 + sn];
#pragma unroll
    for (int j = 0; j < 4; ++j) wf[k][j] = w4_lds[(k * 64 + sn) * 4 + j];
  }

  // ======== phase 3: sample + main GEMM, register-pipelined staging ========
  f32x4 acc[2][4];
#pragma unroll
  for (int mfi = 0; mfi < 2; ++mfi)
#pragma unroll
    for (int nf = 0; nf < 4; ++nf) acc[mfi][nf] = (f32x4){0.f, 0.f, 0.f, 0.f};

  f16x4 sv[9];
#define GATHER(CB)                                                     \
  {                                                                    \
    const char* xc = xb + (CB) * 128 + cs * 16;                        \
    _Pragma("unroll") for (int k = 0; k < 9; ++k) {                    \
      unsigned pv = pkv[k];                                            \
      const char* p00 = xc + ((size_t)(pv & 0xFFFu) << 10);            \
      int dxb = (int)(pv & 0x1000u) >> 2;  /* 0 or 1024   */           \
      int dyb = (int)(pv & 0x2000u) << 3;  /* 0 or 65536  */           \
      f32x4 c00 = *(const f32x4*)(p00);                                \
      f32x4 c01 = *(const f32x4*)(p00 + dxb);                          \
      f32x4 c10 = *(const f32x4*)(p00 + dyb);                          \
      f32x4 c11 = *(const f32x4*)(p00 + dyb + dxb);                    \
      f32x4 v = (f32x4){0.f, 0.f, 0.f, 0.f};                           \
      v = madv(c00, wf[k][0], v);                                      \
      v = madv(c01, wf[k][1], v);                                      \
      v = madv(c10, wf[k][2], v);                                      \
      v = madv(c11, wf[k][3], v);                                      \
      sv[k] = __builtin_convertvector(v, f16x4);                       \
    }                                                                  \
  }

  GATHER(0);
  __syncthreads();  // pkw register loads done before valT overwrite
  for (int cb = 0; cb < 8; ++cb) {
    {
      char* ldr = smem + sn * RS + cs * 8;
#pragma unroll
      for (int k = 0; k < 9; ++k) *(f16x4*)(ldr + k * 64) = sv[k];
    }
    __syncthreads();
    if (cb < 7) GATHER(cb + 1);  // loads in flight under the MFMA block below
    {
      const unsigned short* wtk = Wt + (size_t)(cb * 9) * 8192 + (wv * 32 + m15) * 32 + q * 8;
#pragma unroll
      for (int ks = 0; ks < 9; ++ks) {
        const unsigned short* wp2 = wtk + ks * 8192;
        f16x8 a0 = *(const f16x8*)(wp2);
        f16x8 a1 = *(const f16x8*)(wp2 + 512);  // +16 o-rows
#pragma unroll
        for (int nf = 0; nf < 4; ++nf) {
          f16x8 bb = *(const f16x8*)(smem + (nf * 16 + m15) * RS + ks * 64 + q * 16);
          acc[0][nf] = __builtin_amdgcn_mfma_f32_16x16x32_f16(a0, bb, acc[0][nf], 0, 0, 0);
          acc[1][nf] = __builtin_amdgcn_mfma_f32_16x16x32_f16(a1, bb, acc[1][nf], 0, 0, 0);
        }
      }
    }
    __syncthreads();
  }

  // ======== epilogue: BN + ReLU; C/D: col=lane&15 (px), row=(lane>>4)*4+r (o) ========
  float* ob = out + (size_t)(b * 256) * HW_ + h * 64;
#pragma unroll
  for (int mfi = 0; mfi < 2; ++mfi)
#pragma unroll
    for (int r = 0; r < 4; ++r) {
      int o = wv * 32 + mfi * 16 + q * 4 + r;
      float sc = scale[o], sh = shift[o];
#pragma unroll
      for (int nf = 0; nf < 4; ++nf) {
        float vv = fmaxf(fmaf(acc[mfi][nf][r], sc, sh), 0.f);
        ob[(size_t)o * HW_ + nf * 16 + m15] = vv;
      }
    }
}

extern "C" void kernel_launch(void* const* d_in, const int* in_sizes, int n_in,
                              void* d_out, int out_size, void* d_ws, size_t ws_size,
                              hipStream_t stream) {
  (void)in_sizes; (void)n_in; (void)out_size; (void)ws_size;
  const float* x = (const float*)d_in[0];
  const float* w_off = (const float*)d_in[1];
  const float* b_off = (const float*)d_in[2];
  const float* weight = (const float*)d_in[3];
  const float* bias = (const float*)d_in[4];
  const float* gamma = (const float*)d_in[5];
  const float* beta = (const float*)d_in[6];
  const float* rmean = (const float*)d_in[7];
  const float* rvar = (const float*)d_in[8];
  char* ws = (char*)d_ws;
  unsigned short* Wt = (unsigned short*)ws;
  unsigned short* Woff = (unsigned short*)(ws + 1179648);
  float* scale = (float*)(ws + 1327104);
  float* shift = (float*)(ws + 1328128);
  float* xT = (float*)(ws + 1329152);
  float* out = (float*)d_out;

  setup_kernel<<<dim3(1280), dim3(256), 0, stream>>>(x, weight, w_off, bias, gamma, beta,
                                                     rmean, rvar, Wt, Woff, scale, shift, xT);
  fused_kernel<<<dim3(256), dim3(512), 0, stream>>>(xT, Wt, Woff, b_off, scale, shift, out);
}